// Round 6
// baseline (114.401 us; speedup 1.0000x reference)
//
#include <hip/hip_runtime.h>

#define BATCH 16384
#define LATENT 128
#define HIDDEN 64
#define INDIM 100
#define KPAD 128
#define TANH_SCALE 2.885390081777927f   // 2*log2(e): exp(2x) = exp2(SCALE*x)

typedef short shortx8 __attribute__((ext_vector_type(8)));
typedef float floatx4 __attribute__((ext_vector_type(4)));
typedef float floatx16 __attribute__((ext_vector_type(16)));

__device__ __forceinline__ short f2bf(float f) {
    union { float f; unsigned u; } v; v.f = f;
    unsigned r = v.u + 0x7FFF + ((v.u >> 16) & 1);   // RNE, inputs finite
    return (short)(r >> 16);
}

#if __has_builtin(__builtin_amdgcn_exp2f)
#define EXP2F(x) __builtin_amdgcn_exp2f(x)
#else
#define EXP2F(x) __exp2f(x)
#endif
#if __has_builtin(__builtin_amdgcn_rcpf)
#define RCPF(x) __builtin_amdgcn_rcpf(x)
#else
#define RCPF(x) (1.0f / (x))
#endif

#define N_U_CHUNKS (BATCH * KPAD / 8)            // 262144
#define N_W_CHUNKS (LATENT * HIDDEN * KPAD / 8)  // 131072

// --- fused pre-pass, 32x32x16 fragment order ---------------------------------
// uf chunk c: lane=c&63, kt=(c>>6)&7, gg=c>>9.  row = gg*32+(lane&31),
//   k = kt*16 + (lane>>5)*8 + j   (B-frag of v_mfma_f32_32x32x16_bf16).
// wf chunk c2: lane, kt as above, ht=(c2>>9)&1, lat=c2>>10.
//   h = ht*32+(lane&31), same k mapping (A-frag). W1/b1 pre-scaled by
//   2*log2(e); bias lives at k=100 (u carries 1.0 there), k>100 zero.
// Final block: b2eff[lat] = b2[lat] + sum_h W2[lat][h]  (tanh algebra). ---
__global__ __launch_bounds__(256) void prep_all(const float* __restrict__ u,
                                                const float* __restrict__ W1,
                                                const float* __restrict__ b1,
                                                const float* __restrict__ W2,
                                                const float* __restrict__ b2,
                                                shortx8* __restrict__ uf,
                                                shortx8* __restrict__ wf,
                                                float* __restrict__ b2eff) {
    int c = blockIdx.x * 256 + threadIdx.x;
    if (c < N_U_CHUNKS) {
        int lane = c & 63;
        int kt = (c >> 6) & 7;
        int gg = c >> 9;
        int row = gg * 32 + (lane & 31);
        int kbase = kt * 16 + ((lane >> 5) << 3);
        shortx8 v;
        if (kbase + 7 < INDIM) {
            const float4* p = (const float4*)(u + row * INDIM + kbase);
            float4 f0 = p[0], f1 = p[1];
            v[0] = f2bf(f0.x); v[1] = f2bf(f0.y); v[2] = f2bf(f0.z); v[3] = f2bf(f0.w);
            v[4] = f2bf(f1.x); v[5] = f2bf(f1.y); v[6] = f2bf(f1.z); v[7] = f2bf(f1.w);
        } else {
#pragma unroll
            for (int j = 0; j < 8; j++) {
                int k = kbase + j;
                float f = (k < INDIM) ? u[row * INDIM + k] : (k == INDIM ? 1.0f : 0.0f);
                v[j] = f2bf(f);
            }
        }
        uf[c] = v;
    } else if (c < N_U_CHUNKS + N_W_CHUNKS) {
        int c2 = c - N_U_CHUNKS;
        int lane = c2 & 63;
        int kt = (c2 >> 6) & 7;
        int ht = (c2 >> 9) & 1;
        int lat = c2 >> 10;
        int h = ht * 32 + (lane & 31);
        int hw = lat * HIDDEN + h;
        int kbase = kt * 16 + ((lane >> 5) << 3);
        shortx8 v;
        if (kbase + 7 < INDIM) {
            const float4* p = (const float4*)(W1 + hw * INDIM + kbase);
            float4 f0 = p[0], f1 = p[1];
            v[0] = f2bf(f0.x * TANH_SCALE); v[1] = f2bf(f0.y * TANH_SCALE);
            v[2] = f2bf(f0.z * TANH_SCALE); v[3] = f2bf(f0.w * TANH_SCALE);
            v[4] = f2bf(f1.x * TANH_SCALE); v[5] = f2bf(f1.y * TANH_SCALE);
            v[6] = f2bf(f1.z * TANH_SCALE); v[7] = f2bf(f1.w * TANH_SCALE);
        } else {
#pragma unroll
            for (int j = 0; j < 8; j++) {
                int k = kbase + j;
                float f = (k < INDIM) ? W1[hw * INDIM + k] * TANH_SCALE
                                      : (k == INDIM ? b1[hw] * TANH_SCALE : 0.0f);
                v[j] = f2bf(f);
            }
        }
        wf[c2] = v;
    } else {
        int lat = c - (N_U_CHUNKS + N_W_CHUNKS);
        if (lat < LATENT) {
            float s = b2[lat];
            const float* wp = W2 + lat * HIDDEN;
#pragma unroll 8
            for (int h = 0; h < HIDDEN; h++) s += wp[h];
            b2eff[lat] = s;
        }
    }
}

// ---------------------------------------------------------------------------
// Round-5: 32x32x16 MFMA restructure.
// Round-4 model: LDS pipe (~27us/CU for A-reads) and VALU (~29us, half of it
// v_exp) are co-limiters at 49us. 32x32x16 halves A-LDS traffic (16 MACs per
// A-byte vs 8), halves MFMA instruction count (64/wave at 8.07cyc vs 128 at
// 4.85), halves B traffic, cuts shuffles 16->4 and pays per-group overhead
// half as often. acc zero-init eliminated: kt=0 MFMA takes a loop-invariant
// zero vector as C (saves ~128 v_mov/wave).
// Layouts: C/D 32x32 proven (m74/m101): col=lane&31,
// row=(reg&3)+8*(reg>>2)+4*(lane>>5). A/B generalize our proven 16x16x32
// mapping: row/col=l&31, k=(l>>5)*8+j.
// Wave = one latent, 4 batch-groups of 32 rows; block = 4 waves same latent,
// full W1 panel (16KB) LDS-resident, staged once.
// grid: 4096 blocks x 256 thr.
// ---------------------------------------------------------------------------
__global__ __launch_bounds__(256) __attribute__((amdgpu_waves_per_eu(4, 8)))
void branch_mlp(const shortx8* __restrict__ uf,
                const shortx8* __restrict__ wf,
                const float* __restrict__ W2,
                const float* __restrict__ b2eff,
                float* __restrict__ out) {
    int tid = threadIdx.x;
    int lane = tid & 63;
    int w = tid >> 6;
    int bx = blockIdx.x;
    int lat = bx >> 5;
    int G0 = (bx & 31) * 16 + w * 4;   // first of 4 batch 32-row groups

    __shared__ shortx8 awf[16 * 64];   // [ht*8+kt][lane] A-frags (16 KB)
    __shared__ float w2s[2][HIDDEN];   // -2*W2, 2 copies (defeats LICM)

    // stage this latent's full wf panel to LDS (once per block)
    {
        const shortx8* src = wf + (size_t)lat * 16 * 64;
#pragma unroll
        for (int j = 0; j < 4; j++) awf[j * 256 + tid] = src[j * 256 + tid];
    }
    if (tid < 128) w2s[tid >> 6][tid & 63] = -2.0f * W2[lat * HIDDEN + (tid & 63)];

    float b2v = b2eff[lat];
    __syncthreads();

    const shortx8* ua = uf + (size_t)G0 * 512 + lane;      // 512 chunks/group
    float* outp = out + (size_t)G0 * 32 * LATENT + lat;
    int l5q = (lane >> 5) << 2;        // 4*(lane>>5), row offset term

    floatx16 z = {};                    // loop-invariant zero C operand

#pragma unroll
    for (int g = 0; g < 4; g++) {
        int lnx = lane;
        asm volatile("" : "+v"(lnx));   // opaque copy: forces per-g LDS re-reads

        shortx8 ub[8];
#pragma unroll
        for (int kt = 0; kt < 8; kt++)
            ub[kt] = ua[g * 512 + kt * 64];

        floatx16 acc[2];                // [ht]: h rows ht*32.., cols batch
        {
            shortx8 a0 = awf[0 * 64 + lnx];
            shortx8 a1 = awf[8 * 64 + lnx];
            acc[0] = __builtin_amdgcn_mfma_f32_32x32x16_bf16(a0, ub[0], z, 0, 0, 0);
            acc[1] = __builtin_amdgcn_mfma_f32_32x32x16_bf16(a1, ub[0], z, 0, 0, 0);
        }
#pragma unroll
        for (int kt = 1; kt < 8; kt++) {
            shortx8 a0 = awf[kt * 64 + lnx];
            shortx8 a1 = awf[(8 + kt) * 64 + lnx];
            acc[0] = __builtin_amdgcn_mfma_f32_32x32x16_bf16(a0, ub[kt], acc[0], 0, 0, 0);
            acc[1] = __builtin_amdgcn_mfma_f32_32x32x16_bf16(a1, ub[kt], acc[1], 0, 0, 0);
        }

        // epilogue: lane holds 32 values, col = lane&31,
        // row(reg=b*4+i) = 8*b + l5q + i (+32 for ht=1)
        float s = 0.0f;
#pragma unroll
        for (int ht = 0; ht < 2; ht++)
#pragma unroll
            for (int b = 0; b < 4; b++) {
                float4 wv = *(const float4*)(&w2s[g & 1][ht * 32 + b * 8 + l5q]);
                float p0 = EXP2F(acc[ht][b * 4 + 0]) + 1.0f;  // exp(2x)+1
                float p1 = EXP2F(acc[ht][b * 4 + 1]) + 1.0f;
                float p2 = EXP2F(acc[ht][b * 4 + 2]) + 1.0f;
                float p3 = EXP2F(acc[ht][b * 4 + 3]) + 1.0f;
                float m01 = p0 * p1, m23 = p2 * p3;
                float n01 = fmaf(wv.x, p1, wv.y * p0);   // w0*p1 + w1*p0
                float n23 = fmaf(wv.z, p3, wv.w * p2);
                float n = fmaf(n01, m23, n23 * m01);     // 4-term numerator
                s = fmaf(n, RCPF(m01 * m23), s);         // one rcp per quad
            }
        s += __shfl_xor(s, 32, 64);     // lane l ^ l+32: complementary rows
        if (lane < 32)
            outp[(g * 32 + lane) * LATENT] = s + b2v;   // + b2 + sum_h w2
    }
}

// --- fp32 fallback (no workspace needed) ---
__global__ __launch_bounds__(256) void fallback_kernel(const float* __restrict__ u, const float* __restrict__ W1,
                                                       const float* __restrict__ b1, const float* __restrict__ W2,
                                                       const float* __restrict__ b2, float* __restrict__ out) {
    int idx = blockIdx.x * 256 + threadIdx.x;
    if (idx >= BATCH * LATENT) return;
    int b = idx >> 7;
    int lat = idx & 127;
    const float* ub = u + b * INDIM;
    float s = 0.0f;
    for (int h = 0; h < HIDDEN; h++) {
        const float* wp = W1 + (lat * HIDDEN + h) * INDIM;
        float dd = b1[lat * HIDDEN + h];
        for (int k = 0; k < INDIM; k++) dd += ub[k] * wp[k];
        s += tanhf(dd) * W2[lat * HIDDEN + h];
    }
    out[idx] = s + b2[lat];
}

extern "C" void kernel_launch(void* const* d_in, const int* in_sizes, int n_in,
                              void* d_out, int out_size, void* d_ws, size_t ws_size,
                              hipStream_t stream) {
    const float* u  = (const float*)d_in[0];
    const float* W1 = (const float*)d_in[1];
    const float* b1 = (const float*)d_in[2];
    const float* W2 = (const float*)d_in[3];
    const float* b2 = (const float*)d_in[4];
    float* out = (float*)d_out;

    const size_t UF_BYTES = (size_t)BATCH * KPAD * 2;           // 4 MiB
    const size_t WF_BYTES = (size_t)LATENT * HIDDEN * KPAD * 2; // 2 MiB
    const size_t B2_BYTES = LATENT * sizeof(float);

    if (ws_size < UF_BYTES + WF_BYTES + B2_BYTES) {
        fallback_kernel<<<(BATCH * LATENT + 255) / 256, 256, 0, stream>>>(u, W1, b1, W2, b2, out);
        return;
    }

    shortx8* uf = (shortx8*)d_ws;
    shortx8* wf = (shortx8*)((char*)d_ws + UF_BYTES);
    float* b2eff = (float*)((char*)d_ws + UF_BYTES + WF_BYTES);

    // 1536 blocks cover uf+wf chunks; +1 block computes b2eff
    prep_all<<<(N_U_CHUNKS + N_W_CHUNKS) / 256 + 1, 256, 0, stream>>>(u, W1, b1, W2, b2, uf, wf, b2eff);
    branch_mlp<<<4096, 256, 0, stream>>>(uf, wf, W2, b2eff, out);
}